// Round 11
// baseline (491.840 us; speedup 1.0000x reference)
//
#include <hip/hip_runtime.h>

// VectorQuantizer forward (VQ-VAE), MI355X/gfx950 — round 11.
// Two-phase MFMA design:
//   P1: bf16 MFMA 16x16x32 computes approx d for all (row, code); per-row min.
//   P2: identical (deterministic) MFMA pass emits candidates d <= min+margin.
//   P3: exact f32 re-check of candidates ONLY, with byte-identical reference
//       semantics (serial ascending-j FMA chain, fl32(fl32(s1+s2)-2acc),
//       first-index tie-break). Margin (1e-3*sqrt(s1)+1e-4) is 4x the provable
//       bf16 error bound 2.44e-4*sqrt(s1), so candidates cover all exact ties;
//       >CANDMAX candidates (never expected) falls back to full exact scan.
// s1/s2 use numpy's pairwise scheme (bit-identical to passing rounds 3-10).

#define NROWS (64 * 4096)            // 262144
#define DIMS 64
#define KCODES 512
#define BLOCK 512                    // 8 waves
#define WAVES 8
#define RPB 128                      // rows per block (16 per wave)
#define GRID (NROWS / RPB)           // 2048 blocks
#define CANDMAX 16
#define WS_S2_OFF 0                  // 512 floats
#define WS_RED_OFF 4096              // GRID doubles (16 KB)

typedef __attribute__((ext_vector_type(8))) __bf16 bf16x8;
typedef __attribute__((ext_vector_type(4))) float f32x4;

// numpy pairwise sum, n=64, scalar path: 8 strided accumulators, serial in i,
// then ((r0+r1)+(r2+r3)) + ((r4+r5)+(r6+r7)).
__device__ __forceinline__ float pairwise64_sq(const float4* v) {
  float a[64];
  #pragma unroll
  for (int c = 0; c < 16; ++c) {
    a[4 * c + 0] = v[c].x * v[c].x;
    a[4 * c + 1] = v[c].y * v[c].y;
    a[4 * c + 2] = v[c].z * v[c].z;
    a[4 * c + 3] = v[c].w * v[c].w;
  }
  float r0 = a[0], r1 = a[1], r2 = a[2], r3 = a[3];
  float r4 = a[4], r5 = a[5], r6 = a[6], r7 = a[7];
  #pragma unroll
  for (int i = 8; i < 64; i += 8) {
    r0 += a[i + 0]; r1 += a[i + 1]; r2 += a[i + 2]; r3 += a[i + 3];
    r4 += a[i + 4]; r5 += a[i + 5]; r6 += a[i + 6]; r7 += a[i + 7];
  }
  return ((r0 + r1) + (r2 + r3)) + ((r4 + r5) + (r6 + r7));
}

// s2_k = numpy-pairwise sum(emb_k^2), precomputed once (bit-identical).
__global__ void vq_s2(const float* __restrict__ emb, float* __restrict__ s2) {
  int k = blockIdx.x * 256 + threadIdx.x;   // grid 2 x 256 = 512
  const float4* row = (const float4*)(emb + (size_t)k * DIMS);
  float4 r[16];
  #pragma unroll
  for (int c = 0; c < 16; ++c) r[c] = row[c];
  s2[k] = pairwise64_sq(r);
}

// Exact reference distance for code k: serial ascending-j f32 FMA chain.
__device__ __forceinline__ float vq_exact(const float4* __restrict__ xp,
                                          const float* __restrict__ emb,
                                          float s1v, float s2k, int k) {
  const float4* ep = (const float4*)(emb + (size_t)k * DIMS);
  float acc = 0.f;
  #pragma unroll
  for (int c = 0; c < 16; ++c) {
    float4 e = ep[c], xc = xp[c];
    acc = fmaf(xc.x, e.x, acc);
    acc = fmaf(xc.y, e.y, acc);
    acc = fmaf(xc.z, e.z, acc);
    acc = fmaf(xc.w, e.w, acc);
  }
  float S = s1v + s2k;                 // fl32(s1 + s2_k)
  return fmaf(-2.0f, acc, S);          // fl32(S - 2*acc)
}

struct LdsM {
  unsigned int cb[KCODES * 32];  // bf16 codebook [512][64], XOR-swizzled, 64 KB
  float s2[KCODES];              // 2 KB
  float s1[RPB];
  float dmin[RPB];
  float thr[RPB];
  int   cnt[RPB];
  int   cand[RPB][CANDMAX];      // 8 KB
  int   kidx[RPB];
  double red[WAVES];
};                               // ~78.4 KB -> 2 blocks/CU

__global__ __launch_bounds__(BLOCK, 2) void vq_main(
    const float* __restrict__ x, const float* __restrict__ emb,
    const float* __restrict__ s2g, float* __restrict__ out_idx,
    float* __restrict__ out_q, double* __restrict__ ws) {
  __shared__ LdsM L;
  const int tid = threadIdx.x;
  const int wid = tid >> 6, lane = tid & 63;
  const int row0 = blockIdx.x * RPB;

  // ---- stage codebook f32->bf16 into LDS, byte ^= ((code&7)<<4) swizzle ----
  #pragma unroll
  for (int i = 0; i < 8; ++i) {
    int c = tid + i * BLOCK;          // 16B-chunk id 0..4095
    int code = c >> 3, seg = c & 7;   // seg = 8 dims
    const float4* ep = (const float4*)(emb + (size_t)code * DIMS + seg * 8);
    float4 u = ep[0], v = ep[1];
    bf16x8 h;
    h[0] = (__bf16)u.x; h[1] = (__bf16)u.y; h[2] = (__bf16)u.z; h[3] = (__bf16)u.w;
    h[4] = (__bf16)v.x; h[5] = (__bf16)v.y; h[6] = (__bf16)v.z; h[7] = (__bf16)v.w;
    int boff = code * 128 + ((seg * 16) ^ ((code & 7) << 4));
    *(bf16x8*)((char*)L.cb + boff) = h;
  }
  if (tid < KCODES) L.s2[tid] = s2g[tid];
  if (tid < RPB) {
    float4 xv[16];
    const float4* p = (const float4*)(x + (size_t)(row0 + tid) * DIMS);
    #pragma unroll
    for (int c = 0; c < 16; ++c) xv[c] = p[c];
    L.s1[tid] = pairwise64_sq(xv);    // exact reference s1
  }
  __syncthreads();

  // ---- A fragments: row = lane&15 (of wave's 16 rows), k = (lane>>4)*8+j ----
  const int rowb = wid * 16 + ((lane >> 4) << 2);  // C/D row base (local)
  const int arow = row0 + wid * 16 + (lane & 15);
  const int kb = (lane >> 4) * 8;
  bf16x8 a0, a1;
  {
    const float* xr = x + (size_t)arow * DIMS + kb;
    float4 u0 = *(const float4*)(xr);
    float4 u1 = *(const float4*)(xr + 4);
    float4 v0 = *(const float4*)(xr + 32);
    float4 v1 = *(const float4*)(xr + 36);
    a0[0] = (__bf16)u0.x; a0[1] = (__bf16)u0.y; a0[2] = (__bf16)u0.z; a0[3] = (__bf16)u0.w;
    a0[4] = (__bf16)u1.x; a0[5] = (__bf16)u1.y; a0[6] = (__bf16)u1.z; a0[7] = (__bf16)u1.w;
    a1[0] = (__bf16)v0.x; a1[1] = (__bf16)v0.y; a1[2] = (__bf16)v0.z; a1[3] = (__bf16)v0.w;
    a1[4] = (__bf16)v1.x; a1[5] = (__bf16)v1.y; a1[6] = (__bf16)v1.z; a1[7] = (__bf16)v1.w;
  }
  const float s10 = L.s1[rowb + 0], s11 = L.s1[rowb + 1];
  const float s12 = L.s1[rowb + 2], s13 = L.s1[rowb + 3];
  const int mycol = lane & 15;
  const int segb = (lane >> 4) * 16;   // byte base within code row (kc=0)

  // ---- pass 1: per-row min of approx d over all codes ----
  float cm0 = 3.4e38f, cm1 = 3.4e38f, cm2 = 3.4e38f, cm3 = 3.4e38f;
  #pragma unroll 2
  for (int cc = 0; cc < 32; ++cc) {
    int code = cc * 16 + mycol;
    int swz = (code & 7) << 4;
    char* rbp = (char*)L.cb + code * 128;
    bf16x8 b0 = *(bf16x8*)(rbp + ((segb) ^ swz));
    bf16x8 b1 = *(bf16x8*)(rbp + ((segb + 64) ^ swz));
    f32x4 acc = {0.f, 0.f, 0.f, 0.f};
    acc = __builtin_amdgcn_mfma_f32_16x16x32_bf16(a0, b0, acc, 0, 0, 0);
    acc = __builtin_amdgcn_mfma_f32_16x16x32_bf16(a1, b1, acc, 0, 0, 0);
    float s2c = L.s2[code];
    float d0 = (s10 + s2c) - 2.f * acc[0];
    float d1 = (s11 + s2c) - 2.f * acc[1];
    float d2 = (s12 + s2c) - 2.f * acc[2];
    float d3 = (s13 + s2c) - 2.f * acc[3];
    cm0 = fminf(cm0, d0); cm1 = fminf(cm1, d1);
    cm2 = fminf(cm2, d2); cm3 = fminf(cm3, d3);
  }
  #pragma unroll
  for (int m = 1; m < 16; m <<= 1) {
    cm0 = fminf(cm0, __shfl_xor(cm0, m));
    cm1 = fminf(cm1, __shfl_xor(cm1, m));
    cm2 = fminf(cm2, __shfl_xor(cm2, m));
    cm3 = fminf(cm3, __shfl_xor(cm3, m));
  }
  if (mycol == 0) {
    L.dmin[rowb + 0] = cm0; L.dmin[rowb + 1] = cm1;
    L.dmin[rowb + 2] = cm2; L.dmin[rowb + 3] = cm3;
  }
  __syncthreads();
  if (tid < RPB) {
    // margin = 4x the provable |d_bf16 - d_f32| bound 2.44e-4*sqrt(s1)
    L.thr[tid] = L.dmin[tid] + (1e-3f * sqrtf(L.s1[tid]) + 1e-4f);
    L.cnt[tid] = 0;
  }
  __syncthreads();

  // ---- pass 2: identical recompute, emit candidates ----
  const float t0 = L.thr[rowb + 0], t1 = L.thr[rowb + 1];
  const float t2 = L.thr[rowb + 2], t3 = L.thr[rowb + 3];
  #pragma unroll 2
  for (int cc = 0; cc < 32; ++cc) {
    int code = cc * 16 + mycol;
    int swz = (code & 7) << 4;
    char* rbp = (char*)L.cb + code * 128;
    bf16x8 b0 = *(bf16x8*)(rbp + ((segb) ^ swz));
    bf16x8 b1 = *(bf16x8*)(rbp + ((segb + 64) ^ swz));
    f32x4 acc = {0.f, 0.f, 0.f, 0.f};
    acc = __builtin_amdgcn_mfma_f32_16x16x32_bf16(a0, b0, acc, 0, 0, 0);
    acc = __builtin_amdgcn_mfma_f32_16x16x32_bf16(a1, b1, acc, 0, 0, 0);
    float s2c = L.s2[code];
    float d0 = (s10 + s2c) - 2.f * acc[0];
    float d1 = (s11 + s2c) - 2.f * acc[1];
    float d2 = (s12 + s2c) - 2.f * acc[2];
    float d3 = (s13 + s2c) - 2.f * acc[3];
    if (d0 <= t0) { int p = atomicAdd(&L.cnt[rowb + 0], 1); if (p < CANDMAX) L.cand[rowb + 0][p] = code; }
    if (d1 <= t1) { int p = atomicAdd(&L.cnt[rowb + 1], 1); if (p < CANDMAX) L.cand[rowb + 1][p] = code; }
    if (d2 <= t2) { int p = atomicAdd(&L.cnt[rowb + 2], 1); if (p < CANDMAX) L.cand[rowb + 2][p] = code; }
    if (d3 <= t3) { int p = atomicAdd(&L.cnt[rowb + 3], 1); if (p < CANDMAX) L.cand[rowb + 3][p] = code; }
  }
  __syncthreads();

  // ---- phase 3: exact f32 re-check of candidates (reference semantics) ----
  double lsum = 0.0;
  if (tid < RPB) {
    const int grow = row0 + tid;
    const float s1v = L.s1[tid];
    const float4* xp = (const float4*)(x + (size_t)grow * DIMS);
    float bestd = 3.4e38f;
    int bestk = KCODES;
    int n = L.cnt[tid];
    if (n > CANDMAX) {               // pathological overflow: full exact scan
      for (int k = 0; k < KCODES; ++k) {
        float dv = vq_exact(xp, emb, s1v, L.s2[k], k);
        if (dv < bestd) { bestd = dv; bestk = k; }
      }
    } else {
      for (int i = 0; i < n; ++i) {  // unordered list; tie -> smallest k
        int k = L.cand[tid][i];
        float dv = vq_exact(xp, emb, s1v, L.s2[k], k);
        if (dv < bestd || (dv == bestd && k < bestk)) { bestd = dv; bestk = k; }
      }
    }
    out_idx[grow] = (float)bestk;
    L.kidx[tid] = bestk;
    lsum = (double)bestd;            // == ||x - e_best||^2 to ~1.5e-5 abs
  }

  // ---- loss partials ----
  #pragma unroll
  for (int off = 32; off > 0; off >>= 1) lsum += __shfl_down(lsum, off);
  if (lane == 0) L.red[wid] = lsum;
  __syncthreads();                   // red + kidx ready
  if (tid == 0) {
    double ssum = 0.0;
    #pragma unroll
    for (int w = 0; w < WAVES; ++w) ssum += L.red[w];
    ws[blockIdx.x] = ssum;
  }

  // ---- coalesced out_q: gather codebook rows (f32, L2-hot) via kidx ----
  const float4* emb4 = (const float4*)emb;
  float4* outq4 = (float4*)out_q;
  #pragma unroll
  for (int it = 0; it < 4; ++it) {
    int idx = it * BLOCK + tid;      // 0..2047
    int rr = idx >> 4, c = idx & 15;
    float4 v = emb4[(size_t)L.kidx[rr] * 16 + c];
    outq4[(size_t)(row0 + rr) * 16 + c] = v;
  }
}

__global__ void vq_loss_finalize(const double* __restrict__ ws,
                                 float* __restrict__ out_loss) {
  double s = 0.0;
  for (int i = threadIdx.x; i < GRID; i += 64) s += ws[i];
  #pragma unroll
  for (int off = 32; off > 0; off >>= 1) s += __shfl_down(s, off);
  if (threadIdx.x == 0)
    *out_loss = (float)(1.25 * s / (double)((size_t)NROWS * DIMS));
}

extern "C" void kernel_launch(void* const* d_in, const int* in_sizes, int n_in,
                              void* d_out, int out_size, void* d_ws, size_t ws_size,
                              hipStream_t stream) {
  (void)in_sizes; (void)n_in; (void)out_size; (void)ws_size;
  const float* x   = (const float*)d_in[0];
  const float* emb = (const float*)d_in[1];
  float* out      = (float*)d_out;
  float* out_idx  = out;                                  // NROWS
  float* out_q    = out + NROWS;                          // NROWS*DIMS
  float* out_loss = out + NROWS + (size_t)NROWS * DIMS;   // 1
  float*  ws_s2  = (float*)((char*)d_ws + WS_S2_OFF);     // 512 floats
  double* ws_red = (double*)((char*)d_ws + WS_RED_OFF);   // GRID doubles

  vq_s2<<<2, 256, 0, stream>>>(emb, ws_s2);
  vq_main<<<GRID, BLOCK, 0, stream>>>(x, emb, ws_s2, out_idx, out_q, ws_red);
  vq_loss_finalize<<<1, 64, 0, stream>>>(ws_red, out_loss);
}